// Round 1
// 706.022 us; speedup vs baseline: 1.0075x; 1.0075x over previous
//
#include <hip/hip_runtime.h>

typedef __bf16 bf16x8 __attribute__((ext_vector_type(8)));
typedef float  f32x4  __attribute__((ext_vector_type(4)));

#define GAS(p) ((const __attribute__((address_space(1))) void*)(p))
#define LAS(p) ((__attribute__((address_space(3))) void*)(p))
#define VMCNT(n) asm volatile("s_waitcnt vmcnt(" #n ")" ::: "memory")

__device__ __forceinline__ float gelu_exact(float x) {
    return 0.5f * x * (1.f + erff(x * 0.70710678118654752440f));
}

enum { EPI_X = 0, EPI_GELU = 1, EPI_OUT = 2 };

// ---------------------------------------------------------------------------
// Stage 1: per-point features. One wave per point, 4 points per 256-thr block.
// G row (192 bf16): [0:40)=fourier, [40:148)=gelu patch-MLP hidden, [148:192)=0.
// ---------------------------------------------------------------------------
__global__ __launch_bounds__(256) void stage1_kernel(
    const float* __restrict__ query, const float* __restrict__ images,
    const float* __restrict__ pm_w1, const float* __restrict__ pm_b1,
    __bf16* __restrict__ G, int* __restrict__ tbuf)
{
    __shared__ float patch[4][28];
    const int wave = threadIdx.x >> 6, lane = threadIdx.x & 63;
    const int p = blockIdx.x * 4 + wave;
    const float* q = query + (size_t)p * 5;
    float u = fminf(fmaxf(q[0], 0.f), 1.f);
    float v = fminf(fmaxf(q[1], 0.f), 1.f);
    int ts = min(max((int)rintf(q[2]), 0), 47);
    int tt = min(max((int)rintf(q[3]), 0), 47);
    int tc = min(max((int)rintf(q[4]), 0), 47);
    const int b = p >> 13;  // N = 8192 points per batch
    if (lane < 27) {
        int c = lane / 9, rem = lane % 9, dy = rem / 3, dx = rem % 3;
        int x = (int)rintf(u * 255.f), y = (int)rintf(v * 255.f);
        int xx = min(max(x + dx - 1, 0), 255);
        int yy = min(max(y + dy - 1, 0), 255);
        size_t idx = ((size_t)((b * 3 + c) * 48 + ts) << 16) + ((size_t)yy << 8) + (size_t)xx;
        patch[wave][lane] = images[idx];
    }
    if (lane < 40) {
        int i = lane % 10;
        float base = (lane < 20) ? u : v;
        float ph = 6.28318530717958647693f * base * exp2f((float)i);
        float val = ((lane / 10) & 1) ? cosf(ph) : sinf(ph);
        G[(size_t)p * 192 + lane] = (__bf16)val;
    }
    for (int j = 148 + lane; j < 192; j += 64) G[(size_t)p * 192 + j] = (__bf16)0.f;
    if (lane < 3) tbuf[p * 3 + lane] = (lane == 0) ? ts : (lane == 1) ? tt : tc;
    __syncthreads();
    for (int j = lane; j < 108; j += 64) {
        float acc = pm_b1[j];
        #pragma unroll
        for (int i2 = 0; i2 < 27; i2++)
            acc = fmaf(patch[wave][i2], pm_w1[i2 * 108 + j], acc);
        G[(size_t)p * 192 + 40 + j] = (__bf16)gelu_exact(acc);
    }
}

// ---------------------------------------------------------------------------
// Prepack: transpose f32 (R x C) -> bf16 (C x R)
// ---------------------------------------------------------------------------
__global__ __launch_bounds__(256) void transpose_to_bf16(
    const float* __restrict__ src, __bf16* __restrict__ dst, int R, int C)
{
    __shared__ float t[32][33];
    const int c0 = blockIdx.x * 32, r0 = blockIdx.y * 32;
    const int tx = threadIdx.x & 31, ty = threadIdx.x >> 5;
    #pragma unroll
    for (int i = 0; i < 32; i += 8)
        t[ty + i][tx] = src[(size_t)(r0 + ty + i) * C + (c0 + tx)];
    __syncthreads();
    #pragma unroll
    for (int i = 0; i < 32; i += 8)
        dst[(size_t)(c0 + ty + i) * R + (r0 + tx)] = (__bf16)t[tx][ty + i];
}

// Wcat_t (768 x 192) bf16: row n, k<40 -> uv_w[k][n]; k<148 -> pm_w2[k-40][n]; else 0
__global__ __launch_bounds__(256) void build_wcat(
    const float* __restrict__ uv_w, const float* __restrict__ pm_w2, __bf16* __restrict__ Wt)
{
    int idx = blockIdx.x * 256 + threadIdx.x;  // < 768*192
    int n = idx / 192, k = idx % 192;
    float v = 0.f;
    if (k < 40) v = uv_w[k * 768 + n];
    else if (k < 148) v = pm_w2[(k - 40) * 768 + n];
    Wt[idx] = (__bf16)v;
}

// ---------------------------------------------------------------------------
// 128x128 bf16 MFMA GEMM (m97-structure), kept for GEMM1 (K=192, embed epilogue)
// ---------------------------------------------------------------------------
template <int EPI, typename OutT>
__global__ __launch_bounds__(256) void gemm_bt(
    const __bf16* __restrict__ A, const __bf16* __restrict__ Bt, int K,
    const float* __restrict__ bias, const float* __restrict__ bias2,
    const int* __restrict__ tbuf,
    const float* __restrict__ e0, const float* __restrict__ e1, const float* __restrict__ e2,
    OutT* __restrict__ Cmat, int N)
{
    __shared__ __attribute__((aligned(16))) __bf16 As[128 * 64];
    __shared__ __attribute__((aligned(16))) __bf16 Bs[128 * 64];
    const int tid = threadIdx.x;
    const int wave = tid >> 6, lane = tid & 63;
    const int wr = wave >> 1, wc = wave & 1;
    const int quad = lane >> 4, l15 = lane & 15;
    const int sw = l15 & 7;

    const int ntiles = N >> 7;
    const int per_super = ntiles << 3;
    const int id = blockIdx.x;
    const int sup = id / per_super, rem = id - sup * per_super;
    const long m0 = (long)(sup * 8 + (rem & 7)) << 7;
    const long n0 = (long)(rem >> 3) << 7;

    f32x4 acc[4][4];
    #pragma unroll
    for (int i = 0; i < 4; i++)
        #pragma unroll
        for (int j = 0; j < 4; j++)
            #pragma unroll
            for (int r = 0; r < 4; r++)
                acc[i][j][r] = 0.f;

    const __bf16* pa[4]; const __bf16* pb[4];
    __bf16* la[4]; __bf16* lb[4];
    #pragma unroll
    for (int t = 0; t < 4; t++) {
        int c = (t * 4 + wave) * 64 + lane;
        int row = c >> 3, s = c & 7, g = s ^ (row & 7);
        pa[t] = A  + (m0 + row) * (long)K + g * 8;
        pb[t] = Bt + (n0 + row) * (long)K + g * 8;
        la[t] = As + (t * 4 + wave) * 512;
        lb[t] = Bs + (t * 4 + wave) * 512;
    }

    for (int kt = 0; kt < K; kt += 64) {
        #pragma unroll
        for (int t = 0; t < 4; t++) {
            __builtin_amdgcn_global_load_lds(GAS(pa[t] + kt), LAS(la[t]), 16, 0, 0);
            __builtin_amdgcn_global_load_lds(GAS(pb[t] + kt), LAS(lb[t]), 16, 0, 0);
        }
        __syncthreads();
        #pragma unroll
        for (int h = 0; h < 2; h++) {
            const int slot = ((h * 4 + quad) ^ sw) * 8;
            bf16x8 af[4], bfv[4];
            #pragma unroll
            for (int i = 0; i < 4; i++)
                af[i] = *(const bf16x8*)&As[(wr * 64 + i * 16 + l15) * 64 + slot];
            #pragma unroll
            for (int j = 0; j < 4; j++)
                bfv[j] = *(const bf16x8*)&Bs[(wc * 64 + j * 16 + l15) * 64 + slot];
            #pragma unroll
            for (int i = 0; i < 4; i++)
                #pragma unroll
                for (int j = 0; j < 4; j++)
                    acc[i][j] = __builtin_amdgcn_mfma_f32_16x16x32_bf16(af[i], bfv[j], acc[i][j], 0, 0, 0);
        }
        __syncthreads();
    }

    #pragma unroll
    for (int i = 0; i < 4; i++) {
        #pragma unroll
        for (int r = 0; r < 4; r++) {
            long row = m0 + wr * 64 + i * 16 + quad * 4 + r;
            int t0 = 0, t1 = 0, t2 = 0;
            if constexpr (EPI == EPI_X) {
                t0 = tbuf[row * 3 + 0];
                t1 = tbuf[row * 3 + 1];
                t2 = tbuf[row * 3 + 2];
            }
            #pragma unroll
            for (int j = 0; j < 4; j++) {
                long col = n0 + wc * 64 + j * 16 + l15;
                float val = acc[i][j][r];
                if constexpr (EPI == EPI_X) {
                    val += bias[col] + bias2[col];
                    val += e0[t0 * 768 + col] + e1[t1 * 768 + col] + e2[t2 * 768 + col];
                    Cmat[row * (long)N + col] = (OutT)val;
                } else if constexpr (EPI == EPI_GELU) {
                    val += bias[col];
                    Cmat[row * (long)N + col] = (OutT)gelu_exact(val);
                } else {
                    val += bias[col];
                    Cmat[row * (long)N + col] = (OutT)val;
                }
            }
        }
    }
}

// ---------------------------------------------------------------------------
// 256x256 deep-pipelined bf16 GEMM (T3+T4+T5): C(MxN) = A(MxK) @ Bt(NxK)^T.
// 512 thr, 8 waves 2(M)x4(N), wave tile 128x64. BK=32, 4 rotating LDS buffers
// (128 KiB dynamic), prefetch depth 3, counted vmcnt(12) so loads stay in
// flight across barriers (never drain to 0 until the final K-tile).
// LDS XOR swizzle: slot (row, s) holds global chunk (row, s ^ ((row>>1)&3)),
// 16B chunks, 4 per 64B row -> conflict-free ds_read_b128 (full-stripe cover).
// Requires: M%256==0, N%256==0, K%32==0, K/32>=4, grid%8 arbitrary.
// ---------------------------------------------------------------------------
template <int EPI, typename OutT>
__global__ __launch_bounds__(512, 2) void gemm256(
    const __bf16* __restrict__ A, const __bf16* __restrict__ Bt, int K,
    const float* __restrict__ bias, OutT* __restrict__ Cmat, int N)
{
    extern __shared__ __attribute__((aligned(16))) __bf16 smem[];
    // A buffers: smem + b*8192  (b<4, each 256 rows x 32 cols = 16 KiB)
    // B buffers: smem + 32768 + b*8192
    const int tid = threadIdx.x;
    const int wave = tid >> 6, lane = tid & 63;
    const int wr = wave >> 2, wc = wave & 3;          // 2 x 4 wave grid
    const int quad = lane >> 4, l15 = lane & 15;

    const int ntiles = N >> 8;
    const int per_super = ntiles << 3;
    const int id = blockIdx.x;
    const int sup = id / per_super, rem = id - sup * per_super;
    const long m0 = (long)(sup * 8 + (rem & 7)) << 8;
    const long n0 = (long)(rem >> 3) << 8;

    f32x4 acc[8][4];
    #pragma unroll
    for (int i = 0; i < 8; i++)
        #pragma unroll
        for (int n = 0; n < 4; n++)
            #pragma unroll
            for (int r = 0; r < 4; r++)
                acc[i][n][r] = 0.f;

    // staging: per K-tile 1024 16B-chunks per matrix; thread covers chunk
    // c = i*512 + tid (i<2). LDS dest linear (wave-uniform base + lane*16);
    // global source pre-swizzled: g = (c&3) ^ ((row>>1)&3).
    const __bf16* srcA[2]; const __bf16* srcB[2];
    int ldsA[2], ldsB[2];
    #pragma unroll
    for (int i = 0; i < 2; i++) {
        int c = i * 512 + tid;
        int row = c >> 2, s = c & 3, g = s ^ ((row >> 1) & 3);
        srcA[i] = A  + (m0 + row) * (long)K + g * 8;
        srcB[i] = Bt + (n0 + row) * (long)K + g * 8;
        ldsA[i] = (i * 512 + wave * 64) * 8;
        ldsB[i] = (i * 512 + wave * 64) * 8;
    }

    auto stage = [&](int t) {
        const int buf = (t & 3) * 8192;
        const long koff = (long)t * 32;
        #pragma unroll
        for (int i = 0; i < 2; i++) {
            __builtin_amdgcn_global_load_lds(GAS(srcA[i] + koff), LAS(smem + buf + ldsA[i]), 16, 0, 0);
            __builtin_amdgcn_global_load_lds(GAS(srcB[i] + koff), LAS(smem + 32768 + buf + ldsB[i]), 16, 0, 0);
        }
    };

    // ds_read addressing: row = (wr*128 + i*16 + l15); chunk = quad ^ ((row>>1)&3).
    // i*16 doesn't change (row>>1)&3, so the swizzle term is per-thread constant.
    const int slot = ((quad ^ ((l15 >> 1) & 3)) * 8);
    const int aoff = (wr * 128 + l15) * 32 + slot;
    const int boff = (wc * 64 + l15) * 32 + slot;

    auto compute = [&](int j) {
        const __bf16* ab = smem + (j & 3) * 8192 + aoff;
        const __bf16* bb = smem + 32768 + (j & 3) * 8192 + boff;
        bf16x8 af[8], bv[4];
        #pragma unroll
        for (int i = 0; i < 8; i++) af[i] = *(const bf16x8*)(ab + i * 512);
        #pragma unroll
        for (int n = 0; n < 4; n++) bv[n] = *(const bf16x8*)(bb + n * 512);
        __builtin_amdgcn_s_setprio(1);
        #pragma unroll
        for (int i = 0; i < 8; i++)
            #pragma unroll
            for (int n = 0; n < 4; n++)
                acc[i][n] = __builtin_amdgcn_mfma_f32_16x16x32_bf16(af[i], bv[n], acc[i][n], 0, 0, 0);
        __builtin_amdgcn_s_setprio(0);
        __builtin_amdgcn_sched_barrier(0);
    };

    const int nk = K >> 5;
    stage(0); stage(1); stage(2);                  // 12 loads in flight
    for (int j = 0; j < nk - 3; ++j) {
        __builtin_amdgcn_s_barrier();              // all reads of buf (j-1)&3 retired
        stage(j + 3);                              // overwrite buf (j-1)&3
        VMCNT(12);                                 // own loads for tile j landed
        __builtin_amdgcn_s_barrier();              // everyone's tile-j loads landed
        __builtin_amdgcn_sched_barrier(0);
        compute(j);
    }
    VMCNT(8);
    __builtin_amdgcn_s_barrier();
    __builtin_amdgcn_sched_barrier(0);
    compute(nk - 3);
    VMCNT(4);
    __builtin_amdgcn_s_barrier();
    __builtin_amdgcn_sched_barrier(0);
    compute(nk - 2);
    VMCNT(0);
    __builtin_amdgcn_s_barrier();
    __builtin_amdgcn_sched_barrier(0);
    compute(nk - 1);

    // C/D layout: col = lane&15, row = quad*4 + reg (measured m89/m91)
    #pragma unroll
    for (int i = 0; i < 8; i++) {
        #pragma unroll
        for (int r = 0; r < 4; r++) {
            const long row = m0 + wr * 128 + i * 16 + quad * 4 + r;
            #pragma unroll
            for (int n = 0; n < 4; n++) {
                const long col = n0 + wc * 64 + n * 16 + l15;
                float val = acc[i][n][r] + bias[col];
                if constexpr (EPI == EPI_GELU)
                    Cmat[row * (long)N + col] = (OutT)gelu_exact(val);
                else
                    Cmat[row * (long)N + col] = (OutT)val;
            }
        }
    }
}

// ---------------------------------------------------------------------------
// workspace layout (bytes, all 256-aligned)
// ---------------------------------------------------------------------------
static constexpr size_t OFF_G  = 0;          // 32768*192*2  = 12582912
static constexpr size_t OFF_T  = 12582912;   // 32768*3*4    = 393216
static constexpr size_t OFF_WC = 12976128;   // 768*192*2    = 294912
static constexpr size_t OFF_W1 = 13271040;   // 3072*768*2   = 4718592
static constexpr size_t OFF_W2 = 17989632;   // 768*3072*2   = 4718592
static constexpr size_t OFF_X  = 22708224;   // 32768*768*2  = 50331648
static constexpr size_t OFF_H2 = 73039872;   // Mc*3072*2

extern "C" void kernel_launch(void* const* d_in, const int* in_sizes, int n_in,
                              void* d_out, int out_size, void* d_ws, size_t ws_size,
                              hipStream_t stream)
{
    const float* query  = (const float*)d_in[0];
    const float* images = (const float*)d_in[1];
    const float* uv_w   = (const float*)d_in[2];
    const float* uv_b   = (const float*)d_in[3];
    const float* e_src  = (const float*)d_in[4];
    const float* e_tgt  = (const float*)d_in[5];
    const float* e_cam  = (const float*)d_in[6];
    const float* pm_w1  = (const float*)d_in[7];
    const float* pm_b1  = (const float*)d_in[8];
    const float* pm_w2  = (const float*)d_in[9];
    const float* pm_b2  = (const float*)d_in[10];
    const float* om_w1  = (const float*)d_in[11];
    const float* om_b1  = (const float*)d_in[12];
    const float* om_w2  = (const float*)d_in[13];
    const float* om_b2  = (const float*)d_in[14];
    float* out = (float*)d_out;
    char* ws = (char*)d_ws;

    __bf16* G    = (__bf16*)(ws + OFF_G);
    int*    tb   = (int*)(ws + OFF_T);
    __bf16* Wcat = (__bf16*)(ws + OFF_WC);
    __bf16* W1t  = (__bf16*)(ws + OFF_W1);
    __bf16* W2t  = (__bf16*)(ws + OFF_W2);
    __bf16* X    = (__bf16*)(ws + OFF_X);
    __bf16* H2   = (__bf16*)(ws + OFF_H2);

    static bool attr_done = false;
    if (!attr_done) {
        hipFuncSetAttribute(reinterpret_cast<const void*>(gemm256<EPI_GELU, __bf16>),
                            hipFuncAttributeMaxDynamicSharedMemorySize, 131072);
        hipFuncSetAttribute(reinterpret_cast<const void*>(gemm256<EPI_OUT, float>),
                            hipFuncAttributeMaxDynamicSharedMemorySize, 131072);
        attr_done = true;
    }

    stage1_kernel<<<8192, 256, 0, stream>>>(query, images, pm_w1, pm_b1, G, tb);
    transpose_to_bf16<<<dim3(3072 / 32, 768 / 32), 256, 0, stream>>>(om_w1, W1t, 768, 3072);
    transpose_to_bf16<<<dim3(768 / 32, 3072 / 32), 256, 0, stream>>>(om_w2, W2t, 3072, 768);
    build_wcat<<<576, 256, 0, stream>>>(uv_w, pm_w2, Wcat);

    // X = G @ Wcat^T + uv_b + pm_b2 + embeds   (M=32768, N=768, K=192)
    gemm_bt<EPI_X, __bf16><<<256 * 6, 256, 0, stream>>>(
        G, Wcat, 192, uv_b, pm_b2, tb, e_src, e_tgt, e_cam, X, 768);

    long Mc = 1024;
    for (long cand = 32768; cand >= 1024; cand >>= 1)
        if (OFF_H2 + (size_t)cand * 3072 * 2 <= ws_size) { Mc = cand; break; }

    for (long m = 0; m < 32768; m += Mc) {
        // H2 = gelu(X @ W1t^T + om_b1)   (Mc x 3072, K=768)
        gemm256<EPI_GELU, __bf16><<<(Mc / 256) * 12, 512, 131072, stream>>>(
            X + m * 768, W1t, 768, om_b1, H2, 3072);
        // out = H2 @ W2t^T + om_b2       (Mc x 768, K=3072)
        gemm256<EPI_OUT, float><<<(Mc / 256) * 3, 512, 131072, stream>>>(
            H2, W2t, 3072, om_b2, out + m * 768, 768);
    }
}

// Round 2
// 692.136 us; speedup vs baseline: 1.0277x; 1.0201x over previous
//
#include <hip/hip_runtime.h>

typedef __bf16 bf16x8 __attribute__((ext_vector_type(8)));
typedef float  f32x4  __attribute__((ext_vector_type(4)));

#define GAS(p) ((const __attribute__((address_space(1))) void*)(p))
#define LAS(p) ((__attribute__((address_space(3))) void*)(p))
#define VMCNT(n) asm volatile("s_waitcnt vmcnt(" #n ")" ::: "memory")
#define NOP_STMT ((void)0)

__device__ __forceinline__ float gelu_exact(float x) {
    return 0.5f * x * (1.f + erff(x * 0.70710678118654752440f));
}

enum { EPI_X = 0, EPI_GELU = 1, EPI_OUT = 2 };

// ---------------------------------------------------------------------------
// Stage 1: per-point features. One wave per point, 4 points per 256-thr block.
// G row (192 bf16): [0:40)=fourier, [40:148)=gelu patch-MLP hidden, [148:192)=0.
// ---------------------------------------------------------------------------
__global__ __launch_bounds__(256) void stage1_kernel(
    const float* __restrict__ query, const float* __restrict__ images,
    const float* __restrict__ pm_w1, const float* __restrict__ pm_b1,
    __bf16* __restrict__ G, int* __restrict__ tbuf)
{
    __shared__ float patch[4][28];
    const int wave = threadIdx.x >> 6, lane = threadIdx.x & 63;
    const int p = blockIdx.x * 4 + wave;
    const float* q = query + (size_t)p * 5;
    float u = fminf(fmaxf(q[0], 0.f), 1.f);
    float v = fminf(fmaxf(q[1], 0.f), 1.f);
    int ts = min(max((int)rintf(q[2]), 0), 47);
    int tt = min(max((int)rintf(q[3]), 0), 47);
    int tc = min(max((int)rintf(q[4]), 0), 47);
    const int b = p >> 13;  // N = 8192 points per batch
    if (lane < 27) {
        int c = lane / 9, rem = lane % 9, dy = rem / 3, dx = rem % 3;
        int x = (int)rintf(u * 255.f), y = (int)rintf(v * 255.f);
        int xx = min(max(x + dx - 1, 0), 255);
        int yy = min(max(y + dy - 1, 0), 255);
        size_t idx = ((size_t)((b * 3 + c) * 48 + ts) << 16) + ((size_t)yy << 8) + (size_t)xx;
        patch[wave][lane] = images[idx];
    }
    if (lane < 40) {
        int i = lane % 10;
        float base = (lane < 20) ? u : v;
        float ph = 6.28318530717958647693f * base * exp2f((float)i);
        float val = ((lane / 10) & 1) ? cosf(ph) : sinf(ph);
        G[(size_t)p * 192 + lane] = (__bf16)val;
    }
    for (int j = 148 + lane; j < 192; j += 64) G[(size_t)p * 192 + j] = (__bf16)0.f;
    if (lane < 3) tbuf[p * 3 + lane] = (lane == 0) ? ts : (lane == 1) ? tt : tc;
    __syncthreads();
    for (int j = lane; j < 108; j += 64) {
        float acc = pm_b1[j];
        #pragma unroll
        for (int i2 = 0; i2 < 27; i2++)
            acc = fmaf(patch[wave][i2], pm_w1[i2 * 108 + j], acc);
        G[(size_t)p * 192 + 40 + j] = (__bf16)gelu_exact(acc);
    }
}

// ---------------------------------------------------------------------------
// Prepack: transpose f32 (R x C) -> bf16 (C x R)
// ---------------------------------------------------------------------------
__global__ __launch_bounds__(256) void transpose_to_bf16(
    const float* __restrict__ src, __bf16* __restrict__ dst, int R, int C)
{
    __shared__ float t[32][33];
    const int c0 = blockIdx.x * 32, r0 = blockIdx.y * 32;
    const int tx = threadIdx.x & 31, ty = threadIdx.x >> 5;
    #pragma unroll
    for (int i = 0; i < 32; i += 8)
        t[ty + i][tx] = src[(size_t)(r0 + ty + i) * C + (c0 + tx)];
    __syncthreads();
    #pragma unroll
    for (int i = 0; i < 32; i += 8)
        dst[(size_t)(c0 + ty + i) * R + (r0 + tx)] = (__bf16)t[tx][ty + i];
}

// Wcat_t (768 x 192) bf16: row n, k<40 -> uv_w[k][n]; k<148 -> pm_w2[k-40][n]; else 0
__global__ __launch_bounds__(256) void build_wcat(
    const float* __restrict__ uv_w, const float* __restrict__ pm_w2, __bf16* __restrict__ Wt)
{
    int idx = blockIdx.x * 256 + threadIdx.x;  // < 768*192
    int n = idx / 192, k = idx % 192;
    float v = 0.f;
    if (k < 40) v = uv_w[k * 768 + n];
    else if (k < 148) v = pm_w2[(k - 40) * 768 + n];
    Wt[idx] = (__bf16)v;
}

// ---------------------------------------------------------------------------
// 128x128 bf16 MFMA GEMM (m97-structure), kept for GEMM1 (K=192, embed epilogue)
// ---------------------------------------------------------------------------
template <int EPI, typename OutT>
__global__ __launch_bounds__(256) void gemm_bt(
    const __bf16* __restrict__ A, const __bf16* __restrict__ Bt, int K,
    const float* __restrict__ bias, const float* __restrict__ bias2,
    const int* __restrict__ tbuf,
    const float* __restrict__ e0, const float* __restrict__ e1, const float* __restrict__ e2,
    OutT* __restrict__ Cmat, int N)
{
    __shared__ __attribute__((aligned(16))) __bf16 As[128 * 64];
    __shared__ __attribute__((aligned(16))) __bf16 Bs[128 * 64];
    const int tid = threadIdx.x;
    const int wave = tid >> 6, lane = tid & 63;
    const int wr = wave >> 1, wc = wave & 1;
    const int quad = lane >> 4, l15 = lane & 15;
    const int sw = l15 & 7;

    const int ntiles = N >> 7;
    const int per_super = ntiles << 3;
    const int id = blockIdx.x;
    const int sup = id / per_super, rem = id - sup * per_super;
    const long m0 = (long)(sup * 8 + (rem & 7)) << 7;
    const long n0 = (long)(rem >> 3) << 7;

    f32x4 acc[4][4];
    #pragma unroll
    for (int i = 0; i < 4; i++)
        #pragma unroll
        for (int j = 0; j < 4; j++)
            #pragma unroll
            for (int r = 0; r < 4; r++)
                acc[i][j][r] = 0.f;

    const __bf16* pa[4]; const __bf16* pb[4];
    __bf16* la[4]; __bf16* lb[4];
    #pragma unroll
    for (int t = 0; t < 4; t++) {
        int c = (t * 4 + wave) * 64 + lane;
        int row = c >> 3, s = c & 7, g = s ^ (row & 7);
        pa[t] = A  + (m0 + row) * (long)K + g * 8;
        pb[t] = Bt + (n0 + row) * (long)K + g * 8;
        la[t] = As + (t * 4 + wave) * 512;
        lb[t] = Bs + (t * 4 + wave) * 512;
    }

    for (int kt = 0; kt < K; kt += 64) {
        #pragma unroll
        for (int t = 0; t < 4; t++) {
            __builtin_amdgcn_global_load_lds(GAS(pa[t] + kt), LAS(la[t]), 16, 0, 0);
            __builtin_amdgcn_global_load_lds(GAS(pb[t] + kt), LAS(lb[t]), 16, 0, 0);
        }
        __syncthreads();
        #pragma unroll
        for (int h = 0; h < 2; h++) {
            const int slot = ((h * 4 + quad) ^ sw) * 8;
            bf16x8 af[4], bfv[4];
            #pragma unroll
            for (int i = 0; i < 4; i++)
                af[i] = *(const bf16x8*)&As[(wr * 64 + i * 16 + l15) * 64 + slot];
            #pragma unroll
            for (int j = 0; j < 4; j++)
                bfv[j] = *(const bf16x8*)&Bs[(wc * 64 + j * 16 + l15) * 64 + slot];
            #pragma unroll
            for (int i = 0; i < 4; i++)
                #pragma unroll
                for (int j = 0; j < 4; j++)
                    acc[i][j] = __builtin_amdgcn_mfma_f32_16x16x32_bf16(af[i], bfv[j], acc[i][j], 0, 0, 0);
        }
        __syncthreads();
    }

    #pragma unroll
    for (int i = 0; i < 4; i++) {
        #pragma unroll
        for (int r = 0; r < 4; r++) {
            long row = m0 + wr * 64 + i * 16 + quad * 4 + r;
            int t0 = 0, t1 = 0, t2 = 0;
            if constexpr (EPI == EPI_X) {
                t0 = tbuf[row * 3 + 0];
                t1 = tbuf[row * 3 + 1];
                t2 = tbuf[row * 3 + 2];
            }
            #pragma unroll
            for (int j = 0; j < 4; j++) {
                long col = n0 + wc * 64 + j * 16 + l15;
                float val = acc[i][j][r];
                if constexpr (EPI == EPI_X) {
                    val += bias[col] + bias2[col];
                    val += e0[t0 * 768 + col] + e1[t1 * 768 + col] + e2[t2 * 768 + col];
                    Cmat[row * (long)N + col] = (OutT)val;
                } else if constexpr (EPI == EPI_GELU) {
                    val += bias[col];
                    Cmat[row * (long)N + col] = (OutT)gelu_exact(val);
                } else {
                    val += bias[col];
                    Cmat[row * (long)N + col] = (OutT)val;
                }
            }
        }
    }
}

// ---------------------------------------------------------------------------
// 256x256 8-phase bf16 GEMM (m201 template port, T3+T4+T5):
// C(MxN) = A(MxK) @ Bt(NxK)^T.  512 thr, 8 waves 2(M)x4(N), wave tile 128x64.
// BK=64, LDS [2 dbuf][2 khalf][256 rows][32 cols] bf16 per matrix = 128 KiB.
// 4 phases per K-tile = (kh,mh) quadrants of 16 MFMA; each phase stages one
// half-tile (2 global_load_lds/thread); vmcnt(4) once per K-tile (2 half-tiles
// always in flight). 64B LDS rows -> fragment reads are contiguous 1KB blocks,
// uniformly spread over banks (8 lanes / 4-bank group) -> no swizzle needed.
// Stagger ledger (tile t):  q1: stage (t+1).A.kh1   q2: (t+1).B.kh1
//                           q3: (t+2).A.kh0         q4: (t+2).B.kh0 + vmcnt(4)
// Every WAR pair (stage overwrites slot last ds_read one phase earlier) is
// separated by that phase's lgkmcnt(0) + barrier.
// Requires: M%256==0, N%256==0, K%64==0, K/64>=2.
// ---------------------------------------------------------------------------
#define PHASE(bufc, khc, mhc, STAGE_STMT, WAIT_STMT) do {                     \
    const __bf16* _ab = As + ((bufc) * 2 + (khc)) * 8192 +                    \
                        (wr * 128 + (mhc) * 64 + l15) * 32 + quad * 8;        \
    bf16x8 af[4];                                                             \
    af[0] = *(const bf16x8*)(_ab);                                            \
    af[1] = *(const bf16x8*)(_ab + 512);                                      \
    af[2] = *(const bf16x8*)(_ab + 1024);                                     \
    af[3] = *(const bf16x8*)(_ab + 1536);                                     \
    if ((mhc) == 0) {                                                         \
        const __bf16* _bb = Bs + ((bufc) * 2 + (khc)) * 8192 +                \
                            (wc * 64 + l15) * 32 + quad * 8;                  \
        bv[0] = *(const bf16x8*)(_bb);                                        \
        bv[1] = *(const bf16x8*)(_bb + 512);                                  \
        bv[2] = *(const bf16x8*)(_bb + 1024);                                 \
        bv[3] = *(const bf16x8*)(_bb + 1536);                                 \
    }                                                                         \
    STAGE_STMT;                                                               \
    WAIT_STMT;                                                                \
    __builtin_amdgcn_sched_barrier(0);                                        \
    __builtin_amdgcn_s_barrier();                                             \
    asm volatile("s_waitcnt lgkmcnt(0)" ::: "memory");                        \
    __builtin_amdgcn_sched_barrier(0);                                        \
    __builtin_amdgcn_s_setprio(1);                                            \
    _Pragma("unroll")                                                         \
    for (int _ii = 0; _ii < 4; _ii++)                                         \
        _Pragma("unroll")                                                     \
        for (int _n = 0; _n < 4; _n++)                                        \
            acc[(mhc) * 4 + _ii][_n] = __builtin_amdgcn_mfma_f32_16x16x32_bf16( \
                af[_ii], bv[_n], acc[(mhc) * 4 + _ii][_n], 0, 0, 0);          \
    __builtin_amdgcn_s_setprio(0);                                            \
    __builtin_amdgcn_sched_barrier(0);                                        \
    __builtin_amdgcn_s_barrier();                                             \
} while (0)

#define STAGE_A(buf, kh, t) do {                                              \
    __bf16* _d = As + ((buf) * 2 + (kh)) * 8192;                              \
    const long _ko = (long)(t) * 64 + (kh) * 32;                              \
    __builtin_amdgcn_global_load_lds(GAS(aSrc0 + _ko), LAS(_d + ldsOff0), 16, 0, 0); \
    __builtin_amdgcn_global_load_lds(GAS(aSrc1 + _ko), LAS(_d + ldsOff1), 16, 0, 0); \
} while (0)

#define STAGE_B(buf, kh, t) do {                                              \
    __bf16* _d = Bs + ((buf) * 2 + (kh)) * 8192;                              \
    const long _ko = (long)(t) * 64 + (kh) * 32;                              \
    __builtin_amdgcn_global_load_lds(GAS(bSrc0 + _ko), LAS(_d + ldsOff0), 16, 0, 0); \
    __builtin_amdgcn_global_load_lds(GAS(bSrc1 + _ko), LAS(_d + ldsOff1), 16, 0, 0); \
} while (0)

template <int EPI, typename OutT>
__global__ __launch_bounds__(512, 2) void gemm256(
    const __bf16* __restrict__ A, const __bf16* __restrict__ Bt, int K,
    const float* __restrict__ bias, OutT* __restrict__ Cmat, int N)
{
    extern __shared__ __attribute__((aligned(16))) __bf16 smem[];
    __bf16* As = smem;            // [2][2][256][32] = 32768 elements
    __bf16* Bs = smem + 32768;
    const int tid = threadIdx.x;
    const int wave = tid >> 6, lane = tid & 63;
    const int wr = wave >> 2, wc = wave & 3;          // 2 x 4 wave grid
    const int quad = lane >> 4, l15 = lane & 15;

    const int ntiles = N >> 8;
    const int per_super = ntiles << 3;
    const int id = blockIdx.x;
    const int sup = id / per_super, rem = id - sup * per_super;
    const long m0 = (long)(sup * 8 + (rem & 7)) << 8;
    const long n0 = (long)(rem >> 3) << 8;

    f32x4 acc[8][4];
    #pragma unroll
    for (int i = 0; i < 8; i++)
        #pragma unroll
        for (int n = 0; n < 4; n++)
            #pragma unroll
            for (int r = 0; r < 4; r++)
                acc[i][n][r] = 0.f;

    // staging per half-tile (256 rows x 32 cols): flat chunk f = i*512 + tid,
    // row = f>>2, col-chunk = f&3 (16B). LDS dest linear: elem f*8.
    const int row0 = tid >> 2, row1 = (512 + tid) >> 2;
    const int c0 = (tid & 3) * 8, c1 = ((512 + tid) & 3) * 8;
    const __bf16* aSrc0 = A  + (m0 + row0) * (long)K + c0;
    const __bf16* aSrc1 = A  + (m0 + row1) * (long)K + c1;
    const __bf16* bSrc0 = Bt + (n0 + row0) * (long)K + c0;
    const __bf16* bSrc1 = Bt + (n0 + row1) * (long)K + c1;
    const int ldsOff0 = wave * 512;          // elements; HW adds lane*16B
    const int ldsOff1 = 4096 + wave * 512;

    const int nk = K >> 6;
    // prologue: tile 0 fully, tile 1 kh0
    STAGE_A(0, 0, 0); STAGE_B(0, 0, 0);
    STAGE_A(0, 1, 0); STAGE_B(0, 1, 0);
    STAGE_A(1, 0, 1); STAGE_B(1, 0, 1);
    VMCNT(4);                                  // tile 0 landed (1.kh0 in flight)
    __builtin_amdgcn_s_barrier();

    bf16x8 bv[4];
    for (int t = 0; t < nk - 2; ++t) {
        const int b = t & 1;
        PHASE(b, 0, 0, STAGE_A(b ^ 1, 1, t + 1), NOP_STMT);
        PHASE(b, 0, 1, STAGE_B(b ^ 1, 1, t + 1), NOP_STMT);
        PHASE(b, 1, 0, STAGE_A(b, 0, t + 2), NOP_STMT);
        PHASE(b, 1, 1, STAGE_B(b, 0, t + 2), VMCNT(4));
    }
    {   // t = nk-2: stage only tile nk-1's kh1 halves
        const int b = (nk - 2) & 1;
        PHASE(b, 0, 0, STAGE_A(b ^ 1, 1, nk - 1), NOP_STMT);
        PHASE(b, 0, 1, STAGE_B(b ^ 1, 1, nk - 1), NOP_STMT);
        PHASE(b, 1, 0, NOP_STMT, NOP_STMT);
        PHASE(b, 1, 1, NOP_STMT, VMCNT(0));
    }
    {   // t = nk-1: all data resident
        const int b = (nk - 1) & 1;
        PHASE(b, 0, 0, NOP_STMT, NOP_STMT);
        PHASE(b, 0, 1, NOP_STMT, NOP_STMT);
        PHASE(b, 1, 0, NOP_STMT, NOP_STMT);
        PHASE(b, 1, 1, NOP_STMT, NOP_STMT);
    }

    // C/D layout: col = lane&15, row = quad*4 + reg (measured m89/m91)
    #pragma unroll
    for (int i = 0; i < 8; i++) {
        #pragma unroll
        for (int r = 0; r < 4; r++) {
            const long row = m0 + wr * 128 + i * 16 + quad * 4 + r;
            #pragma unroll
            for (int n = 0; n < 4; n++) {
                const long col = n0 + wc * 64 + n * 16 + l15;
                float val = acc[i][n][r] + bias[col];
                if constexpr (EPI == EPI_GELU)
                    Cmat[row * (long)N + col] = (OutT)gelu_exact(val);
                else
                    Cmat[row * (long)N + col] = (OutT)val;
            }
        }
    }
}

// ---------------------------------------------------------------------------
// workspace layout (bytes, all 256-aligned)
// ---------------------------------------------------------------------------
static constexpr size_t OFF_G  = 0;          // 32768*192*2  = 12582912
static constexpr size_t OFF_T  = 12582912;   // 32768*3*4    = 393216
static constexpr size_t OFF_WC = 12976128;   // 768*192*2    = 294912
static constexpr size_t OFF_W1 = 13271040;   // 3072*768*2   = 4718592
static constexpr size_t OFF_W2 = 17989632;   // 768*3072*2   = 4718592
static constexpr size_t OFF_X  = 22708224;   // 32768*768*2  = 50331648
static constexpr size_t OFF_H2 = 73039872;   // Mc*3072*2

extern "C" void kernel_launch(void* const* d_in, const int* in_sizes, int n_in,
                              void* d_out, int out_size, void* d_ws, size_t ws_size,
                              hipStream_t stream)
{
    const float* query  = (const float*)d_in[0];
    const float* images = (const float*)d_in[1];
    const float* uv_w   = (const float*)d_in[2];
    const float* uv_b   = (const float*)d_in[3];
    const float* e_src  = (const float*)d_in[4];
    const float* e_tgt  = (const float*)d_in[5];
    const float* e_cam  = (const float*)d_in[6];
    const float* pm_w1  = (const float*)d_in[7];
    const float* pm_b1  = (const float*)d_in[8];
    const float* pm_w2  = (const float*)d_in[9];
    const float* pm_b2  = (const float*)d_in[10];
    const float* om_w1  = (const float*)d_in[11];
    const float* om_b1  = (const float*)d_in[12];
    const float* om_w2  = (const float*)d_in[13];
    const float* om_b2  = (const float*)d_in[14];
    float* out = (float*)d_out;
    char* ws = (char*)d_ws;

    __bf16* G    = (__bf16*)(ws + OFF_G);
    int*    tb   = (int*)(ws + OFF_T);
    __bf16* Wcat = (__bf16*)(ws + OFF_WC);
    __bf16* W1t  = (__bf16*)(ws + OFF_W1);
    __bf16* W2t  = (__bf16*)(ws + OFF_W2);
    __bf16* X    = (__bf16*)(ws + OFF_X);
    __bf16* H2   = (__bf16*)(ws + OFF_H2);

    static bool attr_done = false;
    if (!attr_done) {
        hipFuncSetAttribute(reinterpret_cast<const void*>(gemm256<EPI_GELU, __bf16>),
                            hipFuncAttributeMaxDynamicSharedMemorySize, 131072);
        hipFuncSetAttribute(reinterpret_cast<const void*>(gemm256<EPI_OUT, float>),
                            hipFuncAttributeMaxDynamicSharedMemorySize, 131072);
        attr_done = true;
    }

    stage1_kernel<<<8192, 256, 0, stream>>>(query, images, pm_w1, pm_b1, G, tb);
    transpose_to_bf16<<<dim3(3072 / 32, 768 / 32), 256, 0, stream>>>(om_w1, W1t, 768, 3072);
    transpose_to_bf16<<<dim3(768 / 32, 3072 / 32), 256, 0, stream>>>(om_w2, W2t, 3072, 768);
    build_wcat<<<576, 256, 0, stream>>>(uv_w, pm_w2, Wcat);

    // X = G @ Wcat^T + uv_b + pm_b2 + embeds   (M=32768, N=768, K=192)
    gemm_bt<EPI_X, __bf16><<<256 * 6, 256, 0, stream>>>(
        G, Wcat, 192, uv_b, pm_b2, tb, e_src, e_tgt, e_cam, X, 768);

    long Mc = 1024;
    for (long cand = 32768; cand >= 1024; cand >>= 1)
        if (OFF_H2 + (size_t)cand * 3072 * 2 <= ws_size) { Mc = cand; break; }

    for (long m = 0; m < 32768; m += Mc) {
        // H2 = gelu(X @ W1t^T + om_b1)   (Mc x 3072, K=768)
        gemm256<EPI_GELU, __bf16><<<(Mc / 256) * 12, 512, 131072, stream>>>(
            X + m * 768, W1t, 768, om_b1, H2, 3072);
        // out = H2 @ W2t^T + om_b2       (Mc x 768, K=3072)
        gemm256<EPI_OUT, float><<<(Mc / 256) * 3, 512, 131072, stream>>>(
            H2, W2t, 3072, om_b2, out + m * 768, 768);
    }
}